// Round 15
// baseline (1316.283 us; speedup 1.0000x reference)
//
#include <hip/hip_runtime.h>

#define HID 128
#define NLAY 4

typedef float f32x4 __attribute__((ext_vector_type(4)));
typedef short bf16x8 __attribute__((ext_vector_type(8)));

union FragU { uint4 u; bf16x8 v; };

__device__ __forceinline__ float silu_f(float x) {
  // -O3 without fast-math emits a full div sequence for x/(1+e); use v_rcp (1 ulp).
  float e = __expf(-x);
  return x * __builtin_amdgcn_rcpf(1.0f + e);
}

// pack fp32 -> (hi bf16 in low16, lo bf16 in high16)
__device__ __forceinline__ unsigned int pack_pair(float x) {
  unsigned int bx = __float_as_uint(x);
  unsigned int hi = bx & 0xffff0000u;
  float lof = x - __uint_as_float(hi);
  return (bx >> 16) | (__float_as_uint(lof) & 0xffff0000u);
}

// build A_hi/A_lo fragments (8 elts) from 8 packed pairs (2x uint4)
__device__ __forceinline__ void unpack_frags(const uint4& a, const uint4& b,
                                             FragU& hi, FragU& lo) {
  hi.u.x = __builtin_amdgcn_perm(a.y, a.x, 0x05040100u);
  hi.u.y = __builtin_amdgcn_perm(a.w, a.z, 0x05040100u);
  hi.u.z = __builtin_amdgcn_perm(b.y, b.x, 0x05040100u);
  hi.u.w = __builtin_amdgcn_perm(b.w, b.z, 0x05040100u);
  lo.u.x = __builtin_amdgcn_perm(a.y, a.x, 0x07060302u);
  lo.u.y = __builtin_amdgcn_perm(a.w, a.z, 0x07060302u);
  lo.u.z = __builtin_amdgcn_perm(b.y, b.x, 0x07060302u);
  lo.u.w = __builtin_amdgcn_perm(b.w, b.z, 0x07060302u);
}

// split 8 fp32 into hi/lo bf16 A-fragments (channel order i=0..7)
__device__ __forceinline__ void pack8(const float* uu, FragU& hi, FragU& lo) {
  unsigned int h[8], l[8];
  #pragma unroll
  for (int i = 0; i < 8; ++i) {
    unsigned int b = __float_as_uint(uu[i]);
    h[i] = b >> 16;
    float lof = uu[i] - __uint_as_float(b & 0xffff0000u);
    l[i] = __float_as_uint(lof) >> 16;
  }
  hi.u.x = h[0] | (h[1] << 16);
  hi.u.y = h[2] | (h[3] << 16);
  hi.u.z = h[4] | (h[5] << 16);
  hi.u.w = h[6] | (h[7] << 16);
  lo.u.x = l[0] | (l[1] << 16);
  lo.u.y = l[2] | (l[3] << 16);
  lo.u.z = l[4] | (l[5] << 16);
  lo.u.w = l[6] | (l[7] << 16);
}

// ---------------- batched weight prep: 28 matrices [128k][128o] -> frag streams ----
__global__ void wprep_all_kernel(const float* __restrict__ We1, const float* __restrict__ We2,
                                 const float* __restrict__ Wc1, const float* __restrict__ Wn1,
                                 const float* __restrict__ Wn2, unsigned short* __restrict__ wfrag) {
  int gid = blockIdx.x * 256 + threadIdx.x;
  int mat = gid >> 14;             // 0..27 (uniform per block)
  if (mat >= 28) return;
  int id = gid & 16383;
  int l = mat / 7, j = mat % 7;
  const float* src;
  switch (j) {
    case 0: src = We1 + (size_t)l*257*HID; break;
    case 1: src = We1 + (size_t)l*257*HID + 128*HID; break;
    case 2: src = We2 + (size_t)l*HID*HID; break;
    case 3: src = Wc1 + (size_t)l*HID*HID; break;
    case 4: src = Wn1 + (size_t)l*256*HID; break;
    case 5: src = Wn1 + (size_t)l*256*HID + 128*HID; break;
    default: src = Wn2 + (size_t)l*HID*HID; break;
  }
  unsigned short* out = wfrag + (size_t)mat*32768;
  int i = id & 7;
  int lane = (id >> 3) & 63;
  int obkb = id >> 9;              // kb*8+ob
  int k = (obkb >> 3) * 32 + ((lane >> 4) << 3) + i;
  int col = (obkb & 7) * 16 + (lane & 15);
  float x = src[k * 128 + col];
  unsigned int bx = __float_as_uint(x);
  unsigned int hi = bx & 0xffff0000u;
  float lof = x - __uint_as_float(hi);
  out[id] = (unsigned short)(bx >> 16);
  out[16384 + id] = (unsigned short)(__float_as_uint(lof) >> 16);
}

// ---------------- conditioning: h table (B=8 x 128) ----------------
__global__ void hb_kernel(const float* __restrict__ t, const float* __restrict__ z,
                          const float* __restrict__ te_w1, const float* __restrict__ te_b1,
                          const float* __restrict__ te_w2, const float* __restrict__ te_b2,
                          const float* __restrict__ cp_w, const float* __restrict__ cp_b,
                          float* __restrict__ hb) {
  int b = blockIdx.x;
  int j = threadIdx.x;
  float tv = t[b];
  float e1[16];
  #pragma unroll
  for (int i = 0; i < 16; ++i) e1[i] = silu_f(tv * te_w1[i] + te_b1[i]);
  float acc = cp_b[j];
  for (int i = 0; i < 64; ++i) acc += z[b*64 + i] * cp_w[i*HID + j];
  #pragma unroll
  for (int i = 0; i < 16; ++i) {
    float te = te_b2[i];
    #pragma unroll
    for (int k = 0; k < 16; ++k) te += e1[k] * te_w2[k*16 + i];
    acc += te * cp_w[(64 + i)*HID + j];
  }
  hb[b*HID + j] = acc;
}

__global__ void scatter_h_kernel(const int* __restrict__ batch, const float* __restrict__ hb,
                                 float* __restrict__ h, int V) {
  int idx = blockIdx.x * blockDim.x + threadIdx.x;
  if (idx < V * 32) {
    int v = idx >> 5, c = idx & 31;
    int b = batch[v];
    ((float4*)h)[(size_t)v*32 + c] = ((const float4*)hb)[b*32 + c];
  }
}

__global__ void packx_kernel(const float* __restrict__ pos, float4* __restrict__ x4, int V) {
  int v = blockIdx.x * blockDim.x + threadIdx.x;
  if (v < V) x4[v] = make_float4(pos[3*v], pos[3*v+1], pos[3*v+2], 0.f);
}

// ---------------- CSR build ----------------
__global__ void hist_kernel(const int* __restrict__ rowp, int* __restrict__ cnt, int E) {
  int e = blockIdx.x * blockDim.x + threadIdx.x;
  if (e < E) atomicAdd(&cnt[rowp[e]], 1);
}

__global__ void scan_kernel(const int* __restrict__ cnt, int* __restrict__ offp, int V) {
  __shared__ int s[1024];
  __shared__ int carry_s;
  int tid = threadIdx.x;
  if (tid == 0) carry_s = 0;
  __syncthreads();
  for (int base = 0; base < V; base += 1024) {
    int v = base + tid;
    int val = (v < V) ? cnt[v] : 0;
    s[tid] = val;
    __syncthreads();
    for (int d = 1; d < 1024; d <<= 1) {
      int tval = (tid >= d) ? s[tid - d] : 0;
      __syncthreads();
      s[tid] += tval;
      __syncthreads();
    }
    int c0 = carry_s;
    if (v < V) offp[v] = c0 + s[tid] - val;
    int tot = s[1023];
    __syncthreads();
    if (tid == 0) carry_s = c0 + tot;
    __syncthreads();
  }
  if (tid == 0) offp[V] = carry_s;
}

__global__ void scatter_perm_kernel(const int* __restrict__ rowp, const int* __restrict__ colp,
                                    const int* __restrict__ offp, int* __restrict__ fill,
                                    int* __restrict__ srow, int* __restrict__ scol, int E) {
  int e = blockIdx.x * blockDim.x + threadIdx.x;
  if (e < E) {
    int r = rowp[e];
    int p = offp[r] + atomicAdd(&fill[r], 1);
    srow[p] = r;
    scol[p] = colp[e];
  }
}

// ---------------- node GEMM (MFMA, LDS weights, 32-row tiles) ----------------
// MODE 0: out = A@W; 1: +bias; 2: silu(A@W + addsrc); 3: out += A@W + bias
template<int MODE>
__global__ __launch_bounds__(512, 2) void ngemm_kernel(
    const float* __restrict__ in, const unsigned short* __restrict__ wfr,
    const float* __restrict__ bias, const float* __restrict__ addsrc,
    float* __restrict__ out, int V)
{
  extern __shared__ uint4 ldsB[];   // hi: [0..2047], lo: [2048..4095]
  for (int i = threadIdx.x; i < 4096; i += 512) ldsB[i] = ((const uint4*)wfr)[i];
  __syncthreads();
  const int tid = threadIdx.x;
  const int wave = tid >> 6, lane = tid & 63;
  const int g = lane >> 4, c16 = lane & 15;
  float bias_r[8];
  if (MODE == 1 || MODE == 3) {
    #pragma unroll
    for (int ob = 0; ob < 8; ++ob) bias_r[ob] = bias[ob*16 + c16];
  }
  const int gw = blockIdx.x*8 + wave;
  const int nw = gridDim.x*8;
  const int ntiles = V >> 5;
  for (int tt = gw; tt < ntiles; tt += nw) {
    int vb = tt << 5;
    int rowA0 = vb + c16, rowA1 = vb + 16 + c16;
    f32x4 zero4 = {0.f, 0.f, 0.f, 0.f};
    f32x4 acc[2][8];
    #pragma unroll
    for (int s = 0; s < 2; ++s)
      #pragma unroll
      for (int ob = 0; ob < 8; ++ob) acc[s][ob] = zero4;
    #pragma unroll
    for (int kb = 0; kb < 4; ++kb) {
      int ch0 = kb*32 + g*8;
      FragU Ah[2], Al[2];
      #pragma unroll
      for (int s = 0; s < 2; ++s) {
        const float4* pr = (const float4*)(in + (size_t)(s ? rowA1 : rowA0)*HID + ch0);
        float4 a0 = pr[0], a1 = pr[1];
        float uu[8] = {a0.x, a0.y, a0.z, a0.w, a1.x, a1.y, a1.z, a1.w};
        pack8(uu, Ah[s], Al[s]);
      }
      #pragma unroll
      for (int ob = 0; ob < 8; ++ob) {
        FragU Bh, Bl;
        Bh.u = ldsB[(kb*8 + ob)*64 + lane];
        Bl.u = ldsB[2048 + (kb*8 + ob)*64 + lane];
        #pragma unroll
        for (int s = 0; s < 2; ++s) {
          acc[s][ob] = __builtin_amdgcn_mfma_f32_16x16x32_bf16(Al[s].v, Bh.v, acc[s][ob], 0, 0, 0);
          acc[s][ob] = __builtin_amdgcn_mfma_f32_16x16x32_bf16(Ah[s].v, Bl.v, acc[s][ob], 0, 0, 0);
          acc[s][ob] = __builtin_amdgcn_mfma_f32_16x16x32_bf16(Ah[s].v, Bh.v, acc[s][ob], 0, 0, 0);
        }
      }
    }
    #pragma unroll
    for (int s = 0; s < 2; ++s)
      #pragma unroll
      for (int ob = 0; ob < 8; ++ob)
        #pragma unroll
        for (int r = 0; r < 4; ++r) {
          int v = vb + s*16 + 4*g + r;
          size_t idx = (size_t)v*HID + ob*16 + c16;
          float val = acc[s][ob][r];
          if (MODE == 0) out[idx] = val;
          if (MODE == 1) out[idx] = val + bias_r[ob];
          if (MODE == 2) out[idx] = silu_f(val + addsrc[idx]);
          if (MODE == 3) out[idx] += val + bias_r[ob];
        }
  }
}

// ---------------- fused edge kernel with direct atomic aggregation ----------------
// GEMM1 -> m (LDS tile only) -> GEMM2 -> coef; agg/dx accumulated via run-reduced
// atomics (CSR-sorted rows => short runs). m never touches global memory.
__global__ __launch_bounds__(512, 2) void edge_fused_kernel(
    const int* __restrict__ srow, const int* __restrict__ scol,
    const float4* __restrict__ x4,
    const float* __restrict__ p1, const float* __restrict__ p2,
    const unsigned short* __restrict__ wfrE2, const unsigned short* __restrict__ wfrC1,
    const float* __restrict__ wd2_l, const float* __restrict__ be2_l,
    const float* __restrict__ bc1_l, const float* __restrict__ Wc2_l,
    float* __restrict__ aggb, float* __restrict__ dx, int E)
{
  extern __shared__ uint4 lds[];
  uint4* ldsB = lds;                                   // 8192 uint4 = 128KB
  unsigned int* ldsT = (unsigned int*)(lds + 8192);    // 8 waves * 1024 words (4KB each)
  for (int i = threadIdx.x; i < 4096; i += 512) ldsB[i] = ((const uint4*)wfrE2)[i];
  for (int i = threadIdx.x; i < 4096; i += 512) ldsB[4096 + i] = ((const uint4*)wfrC1)[i];
  __syncthreads();
  const int tid = threadIdx.x;
  const int wave = tid >> 6, lane = tid & 63;
  const int g = lane >> 4, c16 = lane & 15;
  unsigned int* myT = ldsT + wave*1024;
  float be2_r[8], bc1_r[8], wc2_r[8];
  #pragma unroll
  for (int ob = 0; ob < 8; ++ob) {
    be2_r[ob] = be2_l[ob*16 + c16];
    bc1_r[ob] = bc1_l[ob*16 + c16];
    wc2_r[ob] = Wc2_l[ob*16 + c16];
  }
  const int swz = (c16 & 7) << 2;
  const int gw = blockIdx.x*8 + wave;
  const int nw = gridDim.x*8;
  const int ntiles = E >> 5;
  for (int tt = gw; tt < ntiles; tt += nw) {
    int ib = tt << 5;
    int r_[2], c_[2]; float d2_[2], rlx[2], rly[2], rlz[2];
    #pragma unroll
    for (int s = 0; s < 2; ++s) {
      int i = ib + s*16 + c16;
      r_[s] = srow[i]; c_[s] = scol[i];
      float4 xr = x4[r_[s]], xc = x4[c_[s]];
      rlx[s] = xr.x-xc.x; rly[s] = xr.y-xc.y; rlz[s] = xr.z-xc.z;
      d2_[s] = rlx[s]*rlx[s] + rly[s]*rly[s] + rlz[s]*rlz[s];
    }
    // rows of the slots this lane's C-fragments map to: slot s*16 + 4g + r
    int rowv[2][4];
    #pragma unroll
    for (int s = 0; s < 2; ++s)
      #pragma unroll
      for (int r = 0; r < 4; ++r)
        rowv[s][r] = __shfl(r_[s], 4*g + r);
    // ---- GEMM1: u @ We2 (hi/lo) ----
    f32x4 zero4 = {0.f, 0.f, 0.f, 0.f};
    f32x4 acc[2][8];
    #pragma unroll
    for (int s = 0; s < 2; ++s)
      #pragma unroll
      for (int ob = 0; ob < 8; ++ob) acc[s][ob] = zero4;
    #pragma unroll
    for (int kb = 0; kb < 4; ++kb) {
      int ch0 = kb*32 + g*8;
      float4 w0 = *(const float4*)(wd2_l + ch0);
      float4 w1 = *(const float4*)(wd2_l + ch0 + 4);
      FragU Ah[2], Al[2];
      #pragma unroll
      for (int s = 0; s < 2; ++s) {
        const float4* pr1 = (const float4*)(p1 + (size_t)r_[s]*HID + ch0);
        const float4* pr2 = (const float4*)(p2 + (size_t)c_[s]*HID + ch0);
        float4 a0 = pr1[0], a1 = pr1[1];
        float4 b0 = pr2[0], b1 = pr2[1];
        float d2 = d2_[s];
        float uu[8];
        uu[0] = silu_f(a0.x + b0.x + d2*w0.x);
        uu[1] = silu_f(a0.y + b0.y + d2*w0.y);
        uu[2] = silu_f(a0.z + b0.z + d2*w0.z);
        uu[3] = silu_f(a0.w + b0.w + d2*w0.w);
        uu[4] = silu_f(a1.x + b1.x + d2*w1.x);
        uu[5] = silu_f(a1.y + b1.y + d2*w1.y);
        uu[6] = silu_f(a1.z + b1.z + d2*w1.z);
        uu[7] = silu_f(a1.w + b1.w + d2*w1.w);
        pack8(uu, Ah[s], Al[s]);
      }
      #pragma unroll
      for (int ob = 0; ob < 8; ++ob) {
        FragU Bh, Bl;
        Bh.u = ldsB[(kb*8 + ob)*64 + lane];
        Bl.u = ldsB[2048 + (kb*8 + ob)*64 + lane];
        #pragma unroll
        for (int s = 0; s < 2; ++s) {
          acc[s][ob] = __builtin_amdgcn_mfma_f32_16x16x32_bf16(Al[s].v, Bh.v, acc[s][ob], 0, 0, 0);
          acc[s][ob] = __builtin_amdgcn_mfma_f32_16x16x32_bf16(Ah[s].v, Bl.v, acc[s][ob], 0, 0, 0);
          acc[s][ob] = __builtin_amdgcn_mfma_f32_16x16x32_bf16(Ah[s].v, Bh.v, acc[s][ob], 0, 0, 0);
        }
      }
    }
    // ---- per half: two 64-channel phases through the 4KB tile ----
    #pragma unroll
    for (int s = 0; s < 2; ++s) {
      f32x4 acc2[8];
      #pragma unroll
      for (int ob = 0; ob < 8; ++ob) acc2[ob] = zero4;
      #pragma unroll
      for (int p = 0; p < 2; ++p) {
        // epilogue -> tile + run-reduced atomic agg accumulation
        #pragma unroll
        for (int ob4 = 0; ob4 < 4; ++ob4) {
          int ob = p*4 + ob4;
          float mv[4];
          #pragma unroll
          for (int r = 0; r < 4; ++r) {
            int row = 4*g + r;
            float mval = silu_f(acc[s][ob][r] + be2_r[ob]);
            mv[r] = mval;
            myT[(row << 6) + ((ob4*16 + c16) ^ ((row & 7) << 2))] = pack_pair(mval);
          }
          int cur = rowv[s][0];
          float sum = mv[0];
          #pragma unroll
          for (int r = 1; r < 4; ++r) {
            int rv = rowv[s][r];
            if (rv == cur) sum += mv[r];
            else {
              atomicAdd(&aggb[(size_t)cur*HID + ob*16 + c16], sum);
              cur = rv; sum = mv[r];
            }
          }
          atomicAdd(&aggb[(size_t)cur*HID + ob*16 + c16], sum);
        }
        // GEMM2 partial: kb = p*2, p*2+1 (Wc1 hi/lo)
        #pragma unroll
        for (int kbl = 0; kbl < 2; ++kbl) {
          int kb = p*2 + kbl;
          int col0 = kbl*32 + g*8;
          uint4 a = *(const uint4*)&myT[(c16 << 6) + (col0 ^ swz)];
          uint4 b = *(const uint4*)&myT[(c16 << 6) + ((col0 + 4) ^ swz)];
          FragU Ah, Al;
          unpack_frags(a, b, Ah, Al);
          #pragma unroll
          for (int ob = 0; ob < 8; ++ob) {
            FragU Bh, Bl;
            Bh.u = ldsB[4096 + (kb*8 + ob)*64 + lane];
            Bl.u = ldsB[6144 + (kb*8 + ob)*64 + lane];
            acc2[ob] = __builtin_amdgcn_mfma_f32_16x16x32_bf16(Al.v, Bh.v, acc2[ob], 0, 0, 0);
            acc2[ob] = __builtin_amdgcn_mfma_f32_16x16x32_bf16(Ah.v, Bl.v, acc2[ob], 0, 0, 0);
            acc2[ob] = __builtin_amdgcn_mfma_f32_16x16x32_bf16(Ah.v, Bh.v, acc2[ob], 0, 0, 0);
          }
        }
      }
      // coef reduce + run-reduced atomic dx accumulation
      float part[4] = {0.f, 0.f, 0.f, 0.f};
      #pragma unroll
      for (int ob = 0; ob < 8; ++ob)
        #pragma unroll
        for (int r = 0; r < 4; ++r) {
          float tv = silu_f(acc2[ob][r] + bc1_r[ob]);
          part[r] += tv * wc2_r[ob];
        }
      #pragma unroll
      for (int r = 0; r < 4; ++r) {
        #pragma unroll
        for (int m = 1; m < 16; m <<= 1) part[r] += __shfl_xor(part[r], m);
      }
      float cxv[4], cyv[4], czv[4];
      #pragma unroll
      for (int r = 0; r < 4; ++r) {
        float sx = __shfl(rlx[s], 4*g + r);
        float sy = __shfl(rly[s], 4*g + r);
        float sz = __shfl(rlz[s], 4*g + r);
        cxv[r] = sx*part[r]; cyv[r] = sy*part[r]; czv[r] = sz*part[r];
      }
      if (c16 == 0) {
        int cur = rowv[s][0];
        float ax = cxv[0], ay = cyv[0], az = czv[0];
        #pragma unroll
        for (int r = 1; r < 4; ++r) {
          int rv = rowv[s][r];
          if (rv == cur) { ax += cxv[r]; ay += cyv[r]; az += czv[r]; }
          else {
            atomicAdd(&dx[(size_t)cur*4 + 0], ax);
            atomicAdd(&dx[(size_t)cur*4 + 1], ay);
            atomicAdd(&dx[(size_t)cur*4 + 2], az);
            cur = rv; ax = cxv[r]; ay = cyv[r]; az = czv[r];
          }
        }
        atomicAdd(&dx[(size_t)cur*4 + 0], ax);
        atomicAdd(&dx[(size_t)cur*4 + 1], ay);
        atomicAdd(&dx[(size_t)cur*4 + 2], az);
      }
    }
  }
}

// ---------------- apply dx to x4 ----------------
__global__ void adddx_kernel(const float* __restrict__ dx, float4* __restrict__ x4, int V) {
  int v = blockIdx.x * blockDim.x + threadIdx.x;
  if (v < V) {
    float4 xv = x4[v];
    xv.x += dx[(size_t)v*4 + 0];
    xv.y += dx[(size_t)v*4 + 1];
    xv.z += dx[(size_t)v*4 + 2];
    x4[v] = xv;
  }
}

__global__ void vel_kernel(const float4* __restrict__ x4, const float* __restrict__ pos,
                           float* __restrict__ out, int V) {
  int v = blockIdx.x * blockDim.x + threadIdx.x;
  if (v < V) {
    float4 xv = x4[v];
    out[3*v]   = xv.x - pos[3*v];
    out[3*v+1] = xv.y - pos[3*v+1];
    out[3*v+2] = xv.z - pos[3*v+2];
  }
}

extern "C" void kernel_launch(void* const* d_in, const int* in_sizes, int n_in,
                              void* d_out, int out_size, void* d_ws, size_t ws_size,
                              hipStream_t stream) {
  const float* pos   = (const float*)d_in[0];
  const float* t     = (const float*)d_in[1];
  const float* z     = (const float*)d_in[2];
  const int*   ei    = (const int*)d_in[3];
  const int*   batch = (const int*)d_in[4];
  const float* te_w1 = (const float*)d_in[5];
  const float* te_b1 = (const float*)d_in[6];
  const float* te_w2 = (const float*)d_in[7];
  const float* te_b2 = (const float*)d_in[8];
  const float* cp_w  = (const float*)d_in[9];
  const float* cp_b  = (const float*)d_in[10];
  const float* We1   = (const float*)d_in[11];
  const float* be1   = (const float*)d_in[12];
  const float* We2   = (const float*)d_in[13];
  const float* be2   = (const float*)d_in[14];
  const float* Wc1   = (const float*)d_in[15];
  const float* bc1   = (const float*)d_in[16];
  const float* Wc2   = (const float*)d_in[17];
  const float* Wn1   = (const float*)d_in[18];
  const float* bn1   = (const float*)d_in[19];
  const float* Wn2   = (const float*)d_in[20];
  const float* bn2   = (const float*)d_in[21];

  const int V = in_sizes[4];
  const int E = in_sizes[3] / 2;
  const int* rowp = ei;
  const int* colp = ei + E;

  char* base = (char*)d_ws;
  size_t off_b = 0;
  auto alloc = [&](size_t bytes) -> char* {
    char* p = base + off_b;
    off_b += (bytes + 255) & ~(size_t)255;
    return p;
  };
  float*  h     = (float*) alloc((size_t)V*HID*4);
  float*  pA    = (float*) alloc((size_t)V*HID*4);   // p1, later nu1a tmp
  float*  pB    = (float*) alloc((size_t)V*HID*4);   // p2
  float*  aggb  = (float*) alloc((size_t)V*HID*4);   // atomic agg accumulator
  float*  q_buf = (float*) alloc((size_t)V*HID*4);   // q
  float4* x4    = (float4*)alloc((size_t)V*16);
  float*  dx    = (float*) alloc((size_t)V*16);      // atomic position delta
  float*  hb    = (float*) alloc(8*HID*4);
  int*    cnt   = (int*)   alloc((size_t)V*4);
  int*    offp  = (int*)   alloc((size_t)(V+1)*4);
  int*    fill  = (int*)   alloc((size_t)V*4);
  int*    srow  = (int*)   alloc((size_t)E*4);
  int*    scol  = (int*)   alloc((size_t)E*4);
  unsigned short* wfrag = (unsigned short*)alloc((size_t)NLAY*7*32768*sizeof(unsigned short));
  (void)ws_size; (void)n_in; (void)out_size;

  auto wf = [&](int l, int j) -> unsigned short* {
    return wfrag + ((size_t)(l*7 + j))*32768;
  };

  const int NLDS = 65536;
  const int FLDS = 163840;   // full 160 KiB workgroup LDS
  hipFuncSetAttribute((const void*)ngemm_kernel<0>, hipFuncAttributeMaxDynamicSharedMemorySize, NLDS);
  hipFuncSetAttribute((const void*)ngemm_kernel<1>, hipFuncAttributeMaxDynamicSharedMemorySize, NLDS);
  hipFuncSetAttribute((const void*)ngemm_kernel<2>, hipFuncAttributeMaxDynamicSharedMemorySize, NLDS);
  hipFuncSetAttribute((const void*)ngemm_kernel<3>, hipFuncAttributeMaxDynamicSharedMemorySize, NLDS);
  hipFuncSetAttribute((const void*)edge_fused_kernel, hipFuncAttributeMaxDynamicSharedMemorySize, FLDS);

  hb_kernel<<<8, 128, 0, stream>>>(t, z, te_w1, te_b1, te_w2, te_b2, cp_w, cp_b, hb);
  scatter_h_kernel<<<(V*32 + 255)/256, 256, 0, stream>>>(batch, hb, h, V);
  packx_kernel<<<(V + 255)/256, 256, 0, stream>>>(pos, x4, V);
  hipMemsetAsync(cnt, 0, (size_t)V*4, stream);
  hipMemsetAsync(fill, 0, (size_t)V*4, stream);
  hist_kernel<<<(E + 255)/256, 256, 0, stream>>>(rowp, cnt, E);
  scan_kernel<<<1, 1024, 0, stream>>>(cnt, offp, V);
  scatter_perm_kernel<<<(E + 255)/256, 256, 0, stream>>>(rowp, colp, offp, fill, srow, scol, E);

  // prep all 28 MFMA B-frag streams in one launch
  wprep_all_kernel<<<28*64, 256, 0, stream>>>(We1, We2, Wc1, Wn1, Wn2, wfrag);

  const int ngrid = ((V >> 5) + 7) / 8;    // 32-row tiles, 8 waves/block
  const int egrid = 256;                   // 1 block/CU (full-LDS), grid-stride

  for (int l = 0; l < NLAY; ++l) {
    const float* wd2_l = We1 + (size_t)l*257*HID + 256*HID;
    const float* Wc2_l = Wc2 + (size_t)l*HID;
    const float* be1_l = be1 + l*HID;
    const float* be2_l = be2 + l*HID;
    const float* bc1_l = bc1 + l*HID;
    const float* bn1_l = bn1 + l*HID;
    const float* bn2_l = bn2 + l*HID;

    ngemm_kernel<1><<<ngrid, 512, NLDS, stream>>>(h, wf(l,0), be1_l, nullptr, pA, V);   // p1+be1
    ngemm_kernel<0><<<ngrid, 512, NLDS, stream>>>(h, wf(l,1), nullptr, nullptr, pB, V); // p2
    hipMemsetAsync(aggb, 0, (size_t)V*HID*4, stream);
    hipMemsetAsync(dx, 0, (size_t)V*16, stream);
    edge_fused_kernel<<<egrid, 512, FLDS, stream>>>(srow, scol, x4, pA, pB,
                                                    wf(l,2), wf(l,3), wd2_l, be2_l,
                                                    bc1_l, Wc2_l, aggb, dx, E);
    adddx_kernel<<<(V + 255)/256, 256, 0, stream>>>(dx, x4, V);
    ngemm_kernel<1><<<ngrid, 512, NLDS, stream>>>(h, wf(l,4), bn1_l, nullptr, pA, V);   // tmp
    ngemm_kernel<2><<<ngrid, 512, NLDS, stream>>>(aggb, wf(l,5), nullptr, pA, q_buf, V); // q
    ngemm_kernel<3><<<ngrid, 512, NLDS, stream>>>(q_buf, wf(l,6), bn2_l, nullptr, h, V); // h+=
  }
  vel_kernel<<<(V + 255)/256, 256, 0, stream>>>(x4, pos, (float*)d_out, V);
}

// Round 16
// 1284.031 us; speedup vs baseline: 1.0251x; 1.0251x over previous
//
#include <hip/hip_runtime.h>

#define HID 128
#define NLAY 4

typedef float f32x4 __attribute__((ext_vector_type(4)));
typedef short bf16x8 __attribute__((ext_vector_type(8)));

union FragU { uint4 u; bf16x8 v; };

__device__ __forceinline__ float silu_f(float x) {
  // -O3 without fast-math emits a full div sequence for x/(1+e); use v_rcp (1 ulp).
  float e = __expf(-x);
  return x * __builtin_amdgcn_rcpf(1.0f + e);
}

// pack fp32 -> (hi bf16 in low16, lo bf16 in high16)
__device__ __forceinline__ unsigned int pack_pair(float x) {
  unsigned int bx = __float_as_uint(x);
  unsigned int hi = bx & 0xffff0000u;
  float lof = x - __uint_as_float(hi);
  return (bx >> 16) | (__float_as_uint(lof) & 0xffff0000u);
}

__device__ __forceinline__ float unpack_sum(unsigned int p) {
  return __uint_as_float(p << 16) + __uint_as_float(p & 0xffff0000u);
}

// build A_hi/A_lo fragments (8 elts) from 8 packed pairs (2x uint4)
__device__ __forceinline__ void unpack_frags(const uint4& a, const uint4& b,
                                             FragU& hi, FragU& lo) {
  hi.u.x = __builtin_amdgcn_perm(a.y, a.x, 0x05040100u);
  hi.u.y = __builtin_amdgcn_perm(a.w, a.z, 0x05040100u);
  hi.u.z = __builtin_amdgcn_perm(b.y, b.x, 0x05040100u);
  hi.u.w = __builtin_amdgcn_perm(b.w, b.z, 0x05040100u);
  lo.u.x = __builtin_amdgcn_perm(a.y, a.x, 0x07060302u);
  lo.u.y = __builtin_amdgcn_perm(a.w, a.z, 0x07060302u);
  lo.u.z = __builtin_amdgcn_perm(b.y, b.x, 0x07060302u);
  lo.u.w = __builtin_amdgcn_perm(b.w, b.z, 0x07060302u);
}

// split 8 fp32 into hi/lo bf16 A-fragments (channel order i=0..7)
__device__ __forceinline__ void pack8(const float* uu, FragU& hi, FragU& lo) {
  unsigned int h[8], l[8];
  #pragma unroll
  for (int i = 0; i < 8; ++i) {
    unsigned int b = __float_as_uint(uu[i]);
    h[i] = b >> 16;
    float lof = uu[i] - __uint_as_float(b & 0xffff0000u);
    l[i] = __float_as_uint(lof) >> 16;
  }
  hi.u.x = h[0] | (h[1] << 16);
  hi.u.y = h[2] | (h[3] << 16);
  hi.u.z = h[4] | (h[5] << 16);
  hi.u.w = h[6] | (h[7] << 16);
  lo.u.x = l[0] | (l[1] << 16);
  lo.u.y = l[2] | (l[3] << 16);
  lo.u.z = l[4] | (l[5] << 16);
  lo.u.w = l[6] | (l[7] << 16);
}

// ---------------- batched weight prep: 28 matrices [128k][128o] -> frag streams ----
__global__ void wprep_all_kernel(const float* __restrict__ We1, const float* __restrict__ We2,
                                 const float* __restrict__ Wc1, const float* __restrict__ Wn1,
                                 const float* __restrict__ Wn2, unsigned short* __restrict__ wfrag) {
  int gid = blockIdx.x * 256 + threadIdx.x;
  int mat = gid >> 14;             // 0..27 (uniform per block)
  if (mat >= 28) return;
  int id = gid & 16383;
  int l = mat / 7, j = mat % 7;
  const float* src;
  switch (j) {
    case 0: src = We1 + (size_t)l*257*HID; break;
    case 1: src = We1 + (size_t)l*257*HID + 128*HID; break;
    case 2: src = We2 + (size_t)l*HID*HID; break;
    case 3: src = Wc1 + (size_t)l*HID*HID; break;
    case 4: src = Wn1 + (size_t)l*256*HID; break;
    case 5: src = Wn1 + (size_t)l*256*HID + 128*HID; break;
    default: src = Wn2 + (size_t)l*HID*HID; break;
  }
  unsigned short* out = wfrag + (size_t)mat*32768;
  int i = id & 7;
  int lane = (id >> 3) & 63;
  int obkb = id >> 9;              // kb*8+ob
  int k = (obkb >> 3) * 32 + ((lane >> 4) << 3) + i;
  int col = (obkb & 7) * 16 + (lane & 15);
  float x = src[k * 128 + col];
  unsigned int bx = __float_as_uint(x);
  unsigned int hi = bx & 0xffff0000u;
  float lof = x - __uint_as_float(hi);
  out[id] = (unsigned short)(bx >> 16);
  out[16384 + id] = (unsigned short)(__float_as_uint(lof) >> 16);
}

// ---------------- conditioning: h table (B=8 x 128) ----------------
__global__ void hb_kernel(const float* __restrict__ t, const float* __restrict__ z,
                          const float* __restrict__ te_w1, const float* __restrict__ te_b1,
                          const float* __restrict__ te_w2, const float* __restrict__ te_b2,
                          const float* __restrict__ cp_w, const float* __restrict__ cp_b,
                          float* __restrict__ hb) {
  int b = blockIdx.x;
  int j = threadIdx.x;
  float tv = t[b];
  float e1[16];
  #pragma unroll
  for (int i = 0; i < 16; ++i) e1[i] = silu_f(tv * te_w1[i] + te_b1[i]);
  float acc = cp_b[j];
  for (int i = 0; i < 64; ++i) acc += z[b*64 + i] * cp_w[i*HID + j];
  #pragma unroll
  for (int i = 0; i < 16; ++i) {
    float te = te_b2[i];
    #pragma unroll
    for (int k = 0; k < 16; ++k) te += e1[k] * te_w2[k*16 + i];
    acc += te * cp_w[(64 + i)*HID + j];
  }
  hb[b*HID + j] = acc;
}

__global__ void scatter_h_kernel(const int* __restrict__ batch, const float* __restrict__ hb,
                                 float* __restrict__ h, int V) {
  int idx = blockIdx.x * blockDim.x + threadIdx.x;
  if (idx < V * 32) {
    int v = idx >> 5, c = idx & 31;
    int b = batch[v];
    ((float4*)h)[(size_t)v*32 + c] = ((const float4*)hb)[b*32 + c];
  }
}

__global__ void packx_kernel(const float* __restrict__ pos, float4* __restrict__ x4, int V) {
  int v = blockIdx.x * blockDim.x + threadIdx.x;
  if (v < V) x4[v] = make_float4(pos[3*v], pos[3*v+1], pos[3*v+2], 0.f);
}

// ---------------- CSR build ----------------
__global__ void hist_kernel(const int* __restrict__ rowp, int* __restrict__ cnt, int E) {
  int e = blockIdx.x * blockDim.x + threadIdx.x;
  if (e < E) atomicAdd(&cnt[rowp[e]], 1);
}

__global__ void scan_kernel(const int* __restrict__ cnt, int* __restrict__ offp, int V) {
  __shared__ int s[1024];
  __shared__ int carry_s;
  int tid = threadIdx.x;
  if (tid == 0) carry_s = 0;
  __syncthreads();
  for (int base = 0; base < V; base += 1024) {
    int v = base + tid;
    int val = (v < V) ? cnt[v] : 0;
    s[tid] = val;
    __syncthreads();
    for (int d = 1; d < 1024; d <<= 1) {
      int tval = (tid >= d) ? s[tid - d] : 0;
      __syncthreads();
      s[tid] += tval;
      __syncthreads();
    }
    int c0 = carry_s;
    if (v < V) offp[v] = c0 + s[tid] - val;
    int tot = s[1023];
    __syncthreads();
    if (tid == 0) carry_s = c0 + tot;
    __syncthreads();
  }
  if (tid == 0) offp[V] = carry_s;
}

__global__ void scatter_perm_kernel(const int* __restrict__ rowp, const int* __restrict__ colp,
                                    const int* __restrict__ offp, int* __restrict__ fill,
                                    int* __restrict__ srow, int* __restrict__ scol, int E) {
  int e = blockIdx.x * blockDim.x + threadIdx.x;
  if (e < E) {
    int r = rowp[e];
    int p = offp[r] + atomicAdd(&fill[r], 1);
    srow[p] = r;
    scol[p] = colp[e];
  }
}

// ---------------- node GEMM (MFMA, LDS weights, 32-row tiles) ----------------
// MODE 0: out = A@W; 1: +bias; 2: silu(A@W + addsrc); 3: out += A@W + bias
template<int MODE>
__global__ __launch_bounds__(512, 2) void ngemm_kernel(
    const float* __restrict__ in, const unsigned short* __restrict__ wfr,
    const float* __restrict__ bias, const float* __restrict__ addsrc,
    float* __restrict__ out, int V)
{
  extern __shared__ uint4 ldsB[];   // hi: [0..2047], lo: [2048..4095]
  for (int i = threadIdx.x; i < 4096; i += 512) ldsB[i] = ((const uint4*)wfr)[i];
  __syncthreads();
  const int tid = threadIdx.x;
  const int wave = tid >> 6, lane = tid & 63;
  const int g = lane >> 4, c16 = lane & 15;
  float bias_r[8];
  if (MODE == 1 || MODE == 3) {
    #pragma unroll
    for (int ob = 0; ob < 8; ++ob) bias_r[ob] = bias[ob*16 + c16];
  }
  const int gw = blockIdx.x*8 + wave;
  const int nw = gridDim.x*8;
  const int ntiles = V >> 5;
  for (int tt = gw; tt < ntiles; tt += nw) {
    int vb = tt << 5;
    int rowA0 = vb + c16, rowA1 = vb + 16 + c16;
    f32x4 zero4 = {0.f, 0.f, 0.f, 0.f};
    f32x4 acc[2][8];
    #pragma unroll
    for (int s = 0; s < 2; ++s)
      #pragma unroll
      for (int ob = 0; ob < 8; ++ob) acc[s][ob] = zero4;
    #pragma unroll
    for (int kb = 0; kb < 4; ++kb) {
      int ch0 = kb*32 + g*8;
      FragU Ah[2], Al[2];
      #pragma unroll
      for (int s = 0; s < 2; ++s) {
        const float4* pr = (const float4*)(in + (size_t)(s ? rowA1 : rowA0)*HID + ch0);
        float4 a0 = pr[0], a1 = pr[1];
        float uu[8] = {a0.x, a0.y, a0.z, a0.w, a1.x, a1.y, a1.z, a1.w};
        pack8(uu, Ah[s], Al[s]);
      }
      #pragma unroll
      for (int ob = 0; ob < 8; ++ob) {
        FragU Bh, Bl;
        Bh.u = ldsB[(kb*8 + ob)*64 + lane];
        Bl.u = ldsB[2048 + (kb*8 + ob)*64 + lane];
        #pragma unroll
        for (int s = 0; s < 2; ++s) {
          acc[s][ob] = __builtin_amdgcn_mfma_f32_16x16x32_bf16(Al[s].v, Bh.v, acc[s][ob], 0, 0, 0);
          acc[s][ob] = __builtin_amdgcn_mfma_f32_16x16x32_bf16(Ah[s].v, Bl.v, acc[s][ob], 0, 0, 0);
          acc[s][ob] = __builtin_amdgcn_mfma_f32_16x16x32_bf16(Ah[s].v, Bh.v, acc[s][ob], 0, 0, 0);
        }
      }
    }
    #pragma unroll
    for (int s = 0; s < 2; ++s)
      #pragma unroll
      for (int ob = 0; ob < 8; ++ob)
        #pragma unroll
        for (int r = 0; r < 4; ++r) {
          int v = vb + s*16 + 4*g + r;
          size_t idx = (size_t)v*HID + ob*16 + c16;
          float val = acc[s][ob][r];
          if (MODE == 0) out[idx] = val;
          if (MODE == 1) out[idx] = val + bias_r[ob];
          if (MODE == 2) out[idx] = silu_f(val + addsrc[idx]);
          if (MODE == 3) out[idx] += val + bias_r[ob];
        }
  }
}

// ---------------- fused edge kernel (register-pipelined p-gathers, hoisted wd2) ----
// GEMM1 (We2 hi/lo, LDS) -> per 64-channel phase: epilogue -> 4KB per-wave LDS
// transpose tile (XOR swizzle) -> coalesced m store -> GEMM2 partial (Wc1 hi/lo, LDS)
// LDS: We2 hi/lo 64K + Wc1 hi/lo 64K + 8 waves x 4K = 163840 B (full 160K).
__global__ __launch_bounds__(512, 2) void edge_fused_kernel(
    const int* __restrict__ srow, const int* __restrict__ scol,
    const float4* __restrict__ x4,
    const float* __restrict__ p1, const float* __restrict__ p2,
    const unsigned short* __restrict__ wfrE2, const unsigned short* __restrict__ wfrC1,
    const float* __restrict__ wd2_l, const float* __restrict__ be2_l,
    const float* __restrict__ bc1_l, const float* __restrict__ Wc2_l,
    unsigned int* __restrict__ m_pairs, float4* __restrict__ rc_ws, int E)
{
  extern __shared__ uint4 lds[];
  uint4* ldsB = lds;                                   // 8192 uint4 = 128KB
  unsigned int* ldsT = (unsigned int*)(lds + 8192);    // 8 waves * 1024 words (4KB each)
  for (int i = threadIdx.x; i < 4096; i += 512) ldsB[i] = ((const uint4*)wfrE2)[i];
  for (int i = threadIdx.x; i < 4096; i += 512) ldsB[4096 + i] = ((const uint4*)wfrC1)[i];
  __syncthreads();
  const int tid = threadIdx.x;
  const int wave = tid >> 6, lane = tid & 63;
  const int g = lane >> 4, c16 = lane & 15;
  unsigned int* myT = ldsT + wave*1024;
  float be2_r[8], bc1_r[8], wc2_r[8];
  #pragma unroll
  for (int ob = 0; ob < 8; ++ob) {
    be2_r[ob] = be2_l[ob*16 + c16];
    bc1_r[ob] = bc1_l[ob*16 + c16];
    wc2_r[ob] = Wc2_l[ob*16 + c16];
  }
  // hoist wd2 (loop-invariant: depends only on g, kb)
  float4 wd0[4], wd1[4];
  #pragma unroll
  for (int kb = 0; kb < 4; ++kb) {
    wd0[kb] = *(const float4*)(wd2_l + kb*32 + g*8);
    wd1[kb] = *(const float4*)(wd2_l + kb*32 + g*8 + 4);
  }
  const int swz = (c16 & 7) << 2;
  const int gw = blockIdx.x*8 + wave;
  const int nw = gridDim.x*8;
  const int ntiles = E >> 5;
  for (int tt = gw; tt < ntiles; tt += nw) {
    int ib = tt << 5;
    int r_[2], c_[2]; float d2_[2], rlx[2], rly[2], rlz[2];
    #pragma unroll
    for (int s = 0; s < 2; ++s) {
      int i = ib + s*16 + c16;
      r_[s] = srow[i]; c_[s] = scol[i];
      float4 xr = x4[r_[s]], xc = x4[c_[s]];
      rlx[s] = xr.x-xc.x; rly[s] = xr.y-xc.y; rlz[s] = xr.z-xc.z;
      d2_[s] = rlx[s]*rlx[s] + rly[s]*rly[s] + rlz[s]*rlz[s];
    }
    // ---- GEMM1: u @ We2 (hi/lo), register-pipelined p gathers ----
    f32x4 zero4 = {0.f, 0.f, 0.f, 0.f};
    f32x4 acc[2][8];
    #pragma unroll
    for (int s = 0; s < 2; ++s)
      #pragma unroll
      for (int ob = 0; ob < 8; ++ob) acc[s][ob] = zero4;
    // preload kb=0 raw p vectors
    float4 ca0[2], ca1[2], cb0[2], cb1[2];
    #pragma unroll
    for (int s = 0; s < 2; ++s) {
      const float4* pr1 = (const float4*)(p1 + (size_t)r_[s]*HID + g*8);
      const float4* pr2 = (const float4*)(p2 + (size_t)c_[s]*HID + g*8);
      ca0[s] = pr1[0]; ca1[s] = pr1[1];
      cb0[s] = pr2[0]; cb1[s] = pr2[1];
    }
    #pragma unroll
    for (int kb = 0; kb < 4; ++kb) {
      // issue next-kb loads before this kb's MFMAs
      float4 na0[2], na1[2], nb0[2], nb1[2];
      if (kb < 3) {
        #pragma unroll
        for (int s = 0; s < 2; ++s) {
          const float4* pr1 = (const float4*)(p1 + (size_t)r_[s]*HID + (kb+1)*32 + g*8);
          const float4* pr2 = (const float4*)(p2 + (size_t)c_[s]*HID + (kb+1)*32 + g*8);
          na0[s] = pr1[0]; na1[s] = pr1[1];
          nb0[s] = pr2[0]; nb1[s] = pr2[1];
        }
      }
      FragU Ah[2], Al[2];
      #pragma unroll
      for (int s = 0; s < 2; ++s) {
        float4 a0 = ca0[s], a1 = ca1[s];
        float4 b0 = cb0[s], b1 = cb1[s];
        float d2 = d2_[s];
        float uu[8];
        uu[0] = silu_f(a0.x + b0.x + d2*wd0[kb].x);
        uu[1] = silu_f(a0.y + b0.y + d2*wd0[kb].y);
        uu[2] = silu_f(a0.z + b0.z + d2*wd0[kb].z);
        uu[3] = silu_f(a0.w + b0.w + d2*wd0[kb].w);
        uu[4] = silu_f(a1.x + b1.x + d2*wd1[kb].x);
        uu[5] = silu_f(a1.y + b1.y + d2*wd1[kb].y);
        uu[6] = silu_f(a1.z + b1.z + d2*wd1[kb].z);
        uu[7] = silu_f(a1.w + b1.w + d2*wd1[kb].w);
        pack8(uu, Ah[s], Al[s]);
      }
      #pragma unroll
      for (int ob = 0; ob < 8; ++ob) {
        FragU Bh, Bl;
        Bh.u = ldsB[(kb*8 + ob)*64 + lane];
        Bl.u = ldsB[2048 + (kb*8 + ob)*64 + lane];
        #pragma unroll
        for (int s = 0; s < 2; ++s) {
          acc[s][ob] = __builtin_amdgcn_mfma_f32_16x16x32_bf16(Al[s].v, Bh.v, acc[s][ob], 0, 0, 0);
          acc[s][ob] = __builtin_amdgcn_mfma_f32_16x16x32_bf16(Ah[s].v, Bl.v, acc[s][ob], 0, 0, 0);
          acc[s][ob] = __builtin_amdgcn_mfma_f32_16x16x32_bf16(Ah[s].v, Bh.v, acc[s][ob], 0, 0, 0);
        }
      }
      if (kb < 3) {
        #pragma unroll
        for (int s = 0; s < 2; ++s) {
          ca0[s] = na0[s]; ca1[s] = na1[s];
          cb0[s] = nb0[s]; cb1[s] = nb1[s];
        }
      }
    }
    // ---- per half: two 64-channel phases through the 4KB tile ----
    #pragma unroll
    for (int s = 0; s < 2; ++s) {
      f32x4 acc2[8];
      #pragma unroll
      for (int ob = 0; ob < 8; ++ob) acc2[ob] = zero4;
      #pragma unroll
      for (int p = 0; p < 2; ++p) {
        // epilogue -> tile (channels p*64 .. p*64+63)
        #pragma unroll
        for (int ob4 = 0; ob4 < 4; ++ob4) {
          int ob = p*4 + ob4;
          #pragma unroll
          for (int r = 0; r < 4; ++r) {
            int row = 4*g + r;
            float mval = silu_f(acc[s][ob][r] + be2_r[ob]);
            myT[(row << 6) + ((ob4*16 + c16) ^ ((row & 7) << 2))] = pack_pair(mval);
          }
        }
        // coalesced m store: 16 rows x 64 ch (4 insts of 4 x 256B segments)
        unsigned int* gout = m_pairs + (size_t)(ib + s*16)*HID + p*64;
        #pragma unroll
        for (int inst = 0; inst < 4; ++inst) {
          int flat = inst*256 + lane*4;
          int row = flat >> 6, col = flat & 63;
          uint4 vv = *(const uint4*)&myT[(row << 6) + (col ^ ((row & 7) << 2))];
          *(uint4*)(gout + (size_t)row*HID + col) = vv;
        }
        // GEMM2 partial: kb = p*2, p*2+1 (Wc1 hi/lo)
        #pragma unroll
        for (int kbl = 0; kbl < 2; ++kbl) {
          int kb = p*2 + kbl;
          int col0 = kbl*32 + g*8;
          uint4 a = *(const uint4*)&myT[(c16 << 6) + (col0 ^ swz)];
          uint4 b = *(const uint4*)&myT[(c16 << 6) + ((col0 + 4) ^ swz)];
          FragU Ah, Al;
          unpack_frags(a, b, Ah, Al);
          #pragma unroll
          for (int ob = 0; ob < 8; ++ob) {
            FragU Bh, Bl;
            Bh.u = ldsB[4096 + (kb*8 + ob)*64 + lane];
            Bl.u = ldsB[6144 + (kb*8 + ob)*64 + lane];
            acc2[ob] = __builtin_amdgcn_mfma_f32_16x16x32_bf16(Al.v, Bh.v, acc2[ob], 0, 0, 0);
            acc2[ob] = __builtin_amdgcn_mfma_f32_16x16x32_bf16(Ah.v, Bl.v, acc2[ob], 0, 0, 0);
            acc2[ob] = __builtin_amdgcn_mfma_f32_16x16x32_bf16(Ah.v, Bh.v, acc2[ob], 0, 0, 0);
          }
        }
      }
      // coef reduce + rc_ws
      float part[4] = {0.f, 0.f, 0.f, 0.f};
      #pragma unroll
      for (int ob = 0; ob < 8; ++ob)
        #pragma unroll
        for (int r = 0; r < 4; ++r) {
          float tv = silu_f(acc2[ob][r] + bc1_r[ob]);
          part[r] += tv * wc2_r[ob];
        }
      #pragma unroll
      for (int r = 0; r < 4; ++r) {
        #pragma unroll
        for (int m = 1; m < 16; m <<= 1) part[r] += __shfl_xor(part[r], m);
      }
      #pragma unroll
      for (int r = 0; r < 4; ++r) {
        float sx = __shfl(rlx[s], 4*g + r);
        float sy = __shfl(rly[s], 4*g + r);
        float sz = __shfl(rlz[s], 4*g + r);
        if (c16 == 0) {
          float cf = part[r];
          rc_ws[ib + s*16 + 4*g + r] = make_float4(sx*cf, sy*cf, sz*cf, 0.f);
        }
      }
    }
  }
}

// ---------------- aggregation (streaming, CSR slot order) ----------------
__global__ void agg_kernel(const int* __restrict__ offp,
                           const unsigned int* __restrict__ m_pairs,
                           const float4* __restrict__ rc_ws,
                           float* __restrict__ agg, float4* __restrict__ x4, int V)
{
  int wave = threadIdx.x >> 6, lane = threadIdx.x & 63;
  int v = blockIdx.x*4 + wave;
  if (v >= V) return;
  int s = offp[v], e = offp[v+1];
  float acc0 = 0.f, acc1 = 0.f;
  float rx = 0.f, ry = 0.f, rz = 0.f;
  for (int i = s; i < e; ++i) {
    uint2 mv = ((const uint2*)m_pairs)[(size_t)i*64 + lane];
    acc0 += unpack_sum(mv.x);
    acc1 += unpack_sum(mv.y);
    float4 rc = rc_ws[i];
    rx += rc.x; ry += rc.y; rz += rc.z;
  }
  ((float2*)agg)[(size_t)v*64 + lane] = make_float2(acc0, acc1);
  if (lane == 0) {
    float4 xv = x4[v];
    xv.x += rx; xv.y += ry; xv.z += rz;
    x4[v] = xv;
  }
}

__global__ void vel_kernel(const float4* __restrict__ x4, const float* __restrict__ pos,
                           float* __restrict__ out, int V) {
  int v = blockIdx.x * blockDim.x + threadIdx.x;
  if (v < V) {
    float4 xv = x4[v];
    out[3*v]   = xv.x - pos[3*v];
    out[3*v+1] = xv.y - pos[3*v+1];
    out[3*v+2] = xv.z - pos[3*v+2];
  }
}

extern "C" void kernel_launch(void* const* d_in, const int* in_sizes, int n_in,
                              void* d_out, int out_size, void* d_ws, size_t ws_size,
                              hipStream_t stream) {
  const float* pos   = (const float*)d_in[0];
  const float* t     = (const float*)d_in[1];
  const float* z     = (const float*)d_in[2];
  const int*   ei    = (const int*)d_in[3];
  const int*   batch = (const int*)d_in[4];
  const float* te_w1 = (const float*)d_in[5];
  const float* te_b1 = (const float*)d_in[6];
  const float* te_w2 = (const float*)d_in[7];
  const float* te_b2 = (const float*)d_in[8];
  const float* cp_w  = (const float*)d_in[9];
  const float* cp_b  = (const float*)d_in[10];
  const float* We1   = (const float*)d_in[11];
  const float* be1   = (const float*)d_in[12];
  const float* We2   = (const float*)d_in[13];
  const float* be2   = (const float*)d_in[14];
  const float* Wc1   = (const float*)d_in[15];
  const float* bc1   = (const float*)d_in[16];
  const float* Wc2   = (const float*)d_in[17];
  const float* Wn1   = (const float*)d_in[18];
  const float* bn1   = (const float*)d_in[19];
  const float* Wn2   = (const float*)d_in[20];
  const float* bn2   = (const float*)d_in[21];

  const int V = in_sizes[4];
  const int E = in_sizes[3] / 2;
  const int* rowp = ei;
  const int* colp = ei + E;

  char* base = (char*)d_ws;
  size_t off_b = 0;
  auto alloc = [&](size_t bytes) -> char* {
    char* p = base + off_b;
    off_b += (bytes + 255) & ~(size_t)255;
    return p;
  };
  float*  h     = (float*) alloc((size_t)V*HID*4);
  float*  pA    = (float*) alloc((size_t)V*HID*4);   // p1, later nu1a tmp
  float*  pB    = (float*) alloc((size_t)V*HID*4);   // p2, later agg
  float4* x4    = (float4*)alloc((size_t)V*16);
  char*   m_buf = alloc((size_t)E*HID*4);            // m pairs (uint), later q (float)
  float4* rc_ws = (float4*)alloc((size_t)E*16);
  float*  hb    = (float*) alloc(8*HID*4);
  int*    cnt   = (int*)   alloc((size_t)V*4);
  int*    offp  = (int*)   alloc((size_t)(V+1)*4);
  int*    fill  = (int*)   alloc((size_t)V*4);
  int*    srow  = (int*)   alloc((size_t)E*4);
  int*    scol  = (int*)   alloc((size_t)E*4);
  unsigned short* wfrag = (unsigned short*)alloc((size_t)NLAY*7*32768*sizeof(unsigned short));
  (void)ws_size; (void)n_in; (void)out_size;

  unsigned int* m_pairs = (unsigned int*)m_buf;
  float* q_buf = (float*)m_buf;

  auto wf = [&](int l, int j) -> unsigned short* {
    return wfrag + ((size_t)(l*7 + j))*32768;
  };

  const int NLDS = 65536;
  const int FLDS = 163840;   // full 160 KiB workgroup LDS
  hipFuncSetAttribute((const void*)ngemm_kernel<0>, hipFuncAttributeMaxDynamicSharedMemorySize, NLDS);
  hipFuncSetAttribute((const void*)ngemm_kernel<1>, hipFuncAttributeMaxDynamicSharedMemorySize, NLDS);
  hipFuncSetAttribute((const void*)ngemm_kernel<2>, hipFuncAttributeMaxDynamicSharedMemorySize, NLDS);
  hipFuncSetAttribute((const void*)ngemm_kernel<3>, hipFuncAttributeMaxDynamicSharedMemorySize, NLDS);
  hipFuncSetAttribute((const void*)edge_fused_kernel, hipFuncAttributeMaxDynamicSharedMemorySize, FLDS);

  hb_kernel<<<8, 128, 0, stream>>>(t, z, te_w1, te_b1, te_w2, te_b2, cp_w, cp_b, hb);
  scatter_h_kernel<<<(V*32 + 255)/256, 256, 0, stream>>>(batch, hb, h, V);
  packx_kernel<<<(V + 255)/256, 256, 0, stream>>>(pos, x4, V);
  hipMemsetAsync(cnt, 0, (size_t)V*4, stream);
  hipMemsetAsync(fill, 0, (size_t)V*4, stream);
  hist_kernel<<<(E + 255)/256, 256, 0, stream>>>(rowp, cnt, E);
  scan_kernel<<<1, 1024, 0, stream>>>(cnt, offp, V);
  scatter_perm_kernel<<<(E + 255)/256, 256, 0, stream>>>(rowp, colp, offp, fill, srow, scol, E);

  // prep all 28 MFMA B-frag streams in one launch
  wprep_all_kernel<<<28*64, 256, 0, stream>>>(We1, We2, Wc1, Wn1, Wn2, wfrag);

  const int ngrid = ((V >> 5) + 7) / 8;    // 32-row tiles, 8 waves/block
  const int egrid = 256;                   // 1 block/CU (full-LDS), grid-stride

  for (int l = 0; l < NLAY; ++l) {
    const float* wd2_l = We1 + (size_t)l*257*HID + 256*HID;
    const float* Wc2_l = Wc2 + (size_t)l*HID;
    const float* be1_l = be1 + l*HID;
    const float* be2_l = be2 + l*HID;
    const float* bc1_l = bc1 + l*HID;
    const float* bn1_l = bn1 + l*HID;
    const float* bn2_l = bn2 + l*HID;

    ngemm_kernel<1><<<ngrid, 512, NLDS, stream>>>(h, wf(l,0), be1_l, nullptr, pA, V);   // p1+be1
    ngemm_kernel<0><<<ngrid, 512, NLDS, stream>>>(h, wf(l,1), nullptr, nullptr, pB, V); // p2
    edge_fused_kernel<<<egrid, 512, FLDS, stream>>>(srow, scol, x4, pA, pB,
                                                    wf(l,2), wf(l,3), wd2_l, be2_l,
                                                    bc1_l, Wc2_l, m_pairs, rc_ws, E);
    agg_kernel<<<(V + 3)/4, 256, 0, stream>>>(offp, m_pairs, rc_ws, pB, x4, V);
    ngemm_kernel<1><<<ngrid, 512, NLDS, stream>>>(h, wf(l,4), bn1_l, nullptr, pA, V);   // tmp
    ngemm_kernel<2><<<ngrid, 512, NLDS, stream>>>(pB, wf(l,5), nullptr, pA, q_buf, V);  // q
    ngemm_kernel<3><<<ngrid, 512, NLDS, stream>>>(q_buf, wf(l,6), bn2_l, nullptr, h, V); // h+=
  }
  vel_kernel<<<(V + 255)/256, 256, 0, stream>>>(x4, pos, (float*)d_out, V);
}

// Round 17
// 1220.252 us; speedup vs baseline: 1.0787x; 1.0523x over previous
//
#include <hip/hip_runtime.h>

#define HID 128
#define NLAY 4

typedef float f32x4 __attribute__((ext_vector_type(4)));
typedef short bf16x8 __attribute__((ext_vector_type(8)));

union FragU { uint4 u; bf16x8 v; };

__device__ __forceinline__ float silu_f(float x) {
  // -O3 without fast-math emits a full div sequence for x/(1+e); use v_rcp (1 ulp).
  float e = __expf(-x);
  return x * __builtin_amdgcn_rcpf(1.0f + e);
}

// pack fp32 -> (hi bf16 in low16, lo bf16 in high16)
__device__ __forceinline__ unsigned int pack_pair(float x) {
  unsigned int bx = __float_as_uint(x);
  unsigned int hi = bx & 0xffff0000u;
  float lof = x - __uint_as_float(hi);
  return (bx >> 16) | (__float_as_uint(lof) & 0xffff0000u);
}

__device__ __forceinline__ float unpack_sum(unsigned int p) {
  return __uint_as_float(p << 16) + __uint_as_float(p & 0xffff0000u);
}

// build A_hi/A_lo fragments (8 elts) from 8 packed pairs (2x uint4)
__device__ __forceinline__ void unpack_frags(const uint4& a, const uint4& b,
                                             FragU& hi, FragU& lo) {
  hi.u.x = __builtin_amdgcn_perm(a.y, a.x, 0x05040100u);
  hi.u.y = __builtin_amdgcn_perm(a.w, a.z, 0x05040100u);
  hi.u.z = __builtin_amdgcn_perm(b.y, b.x, 0x05040100u);
  hi.u.w = __builtin_amdgcn_perm(b.w, b.z, 0x05040100u);
  lo.u.x = __builtin_amdgcn_perm(a.y, a.x, 0x07060302u);
  lo.u.y = __builtin_amdgcn_perm(a.w, a.z, 0x07060302u);
  lo.u.z = __builtin_amdgcn_perm(b.y, b.x, 0x07060302u);
  lo.u.w = __builtin_amdgcn_perm(b.w, b.z, 0x07060302u);
}

// split 8 fp32 into hi/lo bf16 A-fragments (channel order i=0..7)
__device__ __forceinline__ void pack8(const float* uu, FragU& hi, FragU& lo) {
  unsigned int h[8], l[8];
  #pragma unroll
  for (int i = 0; i < 8; ++i) {
    unsigned int b = __float_as_uint(uu[i]);
    h[i] = b >> 16;
    float lof = uu[i] - __uint_as_float(b & 0xffff0000u);
    l[i] = __float_as_uint(lof) >> 16;
  }
  hi.u.x = h[0] | (h[1] << 16);
  hi.u.y = h[2] | (h[3] << 16);
  hi.u.z = h[4] | (h[5] << 16);
  hi.u.w = h[6] | (h[7] << 16);
  lo.u.x = l[0] | (l[1] << 16);
  lo.u.y = l[2] | (l[3] << 16);
  lo.u.z = l[4] | (l[5] << 16);
  lo.u.w = l[6] | (l[7] << 16);
}

// ---------------- batched weight prep: 28 matrices [128k][128o] -> frag streams ----
__global__ void wprep_all_kernel(const float* __restrict__ We1, const float* __restrict__ We2,
                                 const float* __restrict__ Wc1, const float* __restrict__ Wn1,
                                 const float* __restrict__ Wn2, unsigned short* __restrict__ wfrag) {
  int gid = blockIdx.x * 256 + threadIdx.x;
  int mat = gid >> 14;             // 0..27 (uniform per block)
  if (mat >= 28) return;
  int id = gid & 16383;
  int l = mat / 7, j = mat % 7;
  const float* src;
  switch (j) {
    case 0: src = We1 + (size_t)l*257*HID; break;
    case 1: src = We1 + (size_t)l*257*HID + 128*HID; break;
    case 2: src = We2 + (size_t)l*HID*HID; break;
    case 3: src = Wc1 + (size_t)l*HID*HID; break;
    case 4: src = Wn1 + (size_t)l*256*HID; break;
    case 5: src = Wn1 + (size_t)l*256*HID + 128*HID; break;
    default: src = Wn2 + (size_t)l*HID*HID; break;
  }
  unsigned short* out = wfrag + (size_t)mat*32768;
  int i = id & 7;
  int lane = (id >> 3) & 63;
  int obkb = id >> 9;              // kb*8+ob
  int k = (obkb >> 3) * 32 + ((lane >> 4) << 3) + i;
  int col = (obkb & 7) * 16 + (lane & 15);
  float x = src[k * 128 + col];
  unsigned int bx = __float_as_uint(x);
  unsigned int hi = bx & 0xffff0000u;
  float lof = x - __uint_as_float(hi);
  out[id] = (unsigned short)(bx >> 16);
  out[16384 + id] = (unsigned short)(__float_as_uint(lof) >> 16);
}

// ---------------- conditioning: h table (B=8 x 128) ----------------
__global__ void hb_kernel(const float* __restrict__ t, const float* __restrict__ z,
                          const float* __restrict__ te_w1, const float* __restrict__ te_b1,
                          const float* __restrict__ te_w2, const float* __restrict__ te_b2,
                          const float* __restrict__ cp_w, const float* __restrict__ cp_b,
                          float* __restrict__ hb) {
  int b = blockIdx.x;
  int j = threadIdx.x;
  float tv = t[b];
  float e1[16];
  #pragma unroll
  for (int i = 0; i < 16; ++i) e1[i] = silu_f(tv * te_w1[i] + te_b1[i]);
  float acc = cp_b[j];
  for (int i = 0; i < 64; ++i) acc += z[b*64 + i] * cp_w[i*HID + j];
  #pragma unroll
  for (int i = 0; i < 16; ++i) {
    float te = te_b2[i];
    #pragma unroll
    for (int k = 0; k < 16; ++k) te += e1[k] * te_w2[k*16 + i];
    acc += te * cp_w[(64 + i)*HID + j];
  }
  hb[b*HID + j] = acc;
}

__global__ void scatter_h_kernel(const int* __restrict__ batch, const float* __restrict__ hb,
                                 float* __restrict__ h, int V) {
  int idx = blockIdx.x * blockDim.x + threadIdx.x;
  if (idx < V * 32) {
    int v = idx >> 5, c = idx & 31;
    int b = batch[v];
    ((float4*)h)[(size_t)v*32 + c] = ((const float4*)hb)[b*32 + c];
  }
}

__global__ void packx_kernel(const float* __restrict__ pos, float4* __restrict__ x4, int V) {
  int v = blockIdx.x * blockDim.x + threadIdx.x;
  if (v < V) x4[v] = make_float4(pos[3*v], pos[3*v+1], pos[3*v+2], 0.f);
}

// ---------------- CSR build ----------------
__global__ void hist_kernel(const int* __restrict__ rowp, int* __restrict__ cnt, int E) {
  int e = blockIdx.x * blockDim.x + threadIdx.x;
  if (e < E) atomicAdd(&cnt[rowp[e]], 1);
}

__global__ void scan_kernel(const int* __restrict__ cnt, int* __restrict__ offp, int V) {
  __shared__ int s[1024];
  __shared__ int carry_s;
  int tid = threadIdx.x;
  if (tid == 0) carry_s = 0;
  __syncthreads();
  for (int base = 0; base < V; base += 1024) {
    int v = base + tid;
    int val = (v < V) ? cnt[v] : 0;
    s[tid] = val;
    __syncthreads();
    for (int d = 1; d < 1024; d <<= 1) {
      int tval = (tid >= d) ? s[tid - d] : 0;
      __syncthreads();
      s[tid] += tval;
      __syncthreads();
    }
    int c0 = carry_s;
    if (v < V) offp[v] = c0 + s[tid] - val;
    int tot = s[1023];
    __syncthreads();
    if (tid == 0) carry_s = c0 + tot;
    __syncthreads();
  }
  if (tid == 0) offp[V] = carry_s;
}

__global__ void scatter_perm_kernel(const int* __restrict__ rowp, const int* __restrict__ colp,
                                    const int* __restrict__ offp, int* __restrict__ fill,
                                    int* __restrict__ srow, int* __restrict__ scol, int E) {
  int e = blockIdx.x * blockDim.x + threadIdx.x;
  if (e < E) {
    int r = rowp[e];
    int p = offp[r] + atomicAdd(&fill[r], 1);
    srow[p] = r;
    scol[p] = colp[e];
  }
}

// ---------------- node GEMM (MFMA, LDS weights, 32-row tiles) ----------------
// MODE 0: out = A@W; 1: +bias; 2: silu(A@W + addsrc); 3: out += A@W + bias
template<int MODE>
__global__ __launch_bounds__(512, 2) void ngemm_kernel(
    const float* __restrict__ in, const unsigned short* __restrict__ wfr,
    const float* __restrict__ bias, const float* __restrict__ addsrc,
    float* __restrict__ out, int V)
{
  extern __shared__ uint4 ldsB[];   // hi: [0..2047], lo: [2048..4095]
  for (int i = threadIdx.x; i < 4096; i += 512) ldsB[i] = ((const uint4*)wfr)[i];
  __syncthreads();
  const int tid = threadIdx.x;
  const int wave = tid >> 6, lane = tid & 63;
  const int g = lane >> 4, c16 = lane & 15;
  float bias_r[8];
  if (MODE == 1 || MODE == 3) {
    #pragma unroll
    for (int ob = 0; ob < 8; ++ob) bias_r[ob] = bias[ob*16 + c16];
  }
  const int gw = blockIdx.x*8 + wave;
  const int nw = gridDim.x*8;
  const int ntiles = V >> 5;
  for (int tt = gw; tt < ntiles; tt += nw) {
    int vb = tt << 5;
    int rowA0 = vb + c16, rowA1 = vb + 16 + c16;
    f32x4 zero4 = {0.f, 0.f, 0.f, 0.f};
    f32x4 acc[2][8];
    #pragma unroll
    for (int s = 0; s < 2; ++s)
      #pragma unroll
      for (int ob = 0; ob < 8; ++ob) acc[s][ob] = zero4;
    #pragma unroll
    for (int kb = 0; kb < 4; ++kb) {
      int ch0 = kb*32 + g*8;
      FragU Ah[2], Al[2];
      #pragma unroll
      for (int s = 0; s < 2; ++s) {
        const float4* pr = (const float4*)(in + (size_t)(s ? rowA1 : rowA0)*HID + ch0);
        float4 a0 = pr[0], a1 = pr[1];
        float uu[8] = {a0.x, a0.y, a0.z, a0.w, a1.x, a1.y, a1.z, a1.w};
        pack8(uu, Ah[s], Al[s]);
      }
      #pragma unroll
      for (int ob = 0; ob < 8; ++ob) {
        FragU Bh, Bl;
        Bh.u = ldsB[(kb*8 + ob)*64 + lane];
        Bl.u = ldsB[2048 + (kb*8 + ob)*64 + lane];
        #pragma unroll
        for (int s = 0; s < 2; ++s) {
          acc[s][ob] = __builtin_amdgcn_mfma_f32_16x16x32_bf16(Al[s].v, Bh.v, acc[s][ob], 0, 0, 0);
          acc[s][ob] = __builtin_amdgcn_mfma_f32_16x16x32_bf16(Ah[s].v, Bl.v, acc[s][ob], 0, 0, 0);
          acc[s][ob] = __builtin_amdgcn_mfma_f32_16x16x32_bf16(Ah[s].v, Bh.v, acc[s][ob], 0, 0, 0);
        }
      }
    }
    #pragma unroll
    for (int s = 0; s < 2; ++s)
      #pragma unroll
      for (int ob = 0; ob < 8; ++ob)
        #pragma unroll
        for (int r = 0; r < 4; ++r) {
          int v = vb + s*16 + 4*g + r;
          size_t idx = (size_t)v*HID + ob*16 + c16;
          float val = acc[s][ob][r];
          if (MODE == 0) out[idx] = val;
          if (MODE == 1) out[idx] = val + bias_r[ob];
          if (MODE == 2) out[idx] = silu_f(val + addsrc[idx]);
          if (MODE == 3) out[idx] += val + bias_r[ob];
        }
  }
}

// ---------------- fused edge kernel (round-14 proven version) ----------------
// GEMM1 (We2 hi/lo, LDS) -> per 64-channel phase: epilogue -> 4KB per-wave LDS
// transpose tile (XOR swizzle) -> coalesced m store -> GEMM2 partial (Wc1 hi/lo, LDS)
// LDS: We2 hi/lo 64K + Wc1 hi/lo 64K + 8 waves x 4K = 163840 B (full 160K).
__global__ __launch_bounds__(512, 2) void edge_fused_kernel(
    const int* __restrict__ srow, const int* __restrict__ scol,
    const float4* __restrict__ x4,
    const float* __restrict__ p1, const float* __restrict__ p2,
    const unsigned short* __restrict__ wfrE2, const unsigned short* __restrict__ wfrC1,
    const float* __restrict__ wd2_l, const float* __restrict__ be2_l,
    const float* __restrict__ bc1_l, const float* __restrict__ Wc2_l,
    unsigned int* __restrict__ m_pairs, float4* __restrict__ rc_ws, int E)
{
  extern __shared__ uint4 lds[];
  uint4* ldsB = lds;                                   // 8192 uint4 = 128KB
  unsigned int* ldsT = (unsigned int*)(lds + 8192);    // 8 waves * 1024 words (4KB each)
  for (int i = threadIdx.x; i < 4096; i += 512) ldsB[i] = ((const uint4*)wfrE2)[i];
  for (int i = threadIdx.x; i < 4096; i += 512) ldsB[4096 + i] = ((const uint4*)wfrC1)[i];
  __syncthreads();
  const int tid = threadIdx.x;
  const int wave = tid >> 6, lane = tid & 63;
  const int g = lane >> 4, c16 = lane & 15;
  unsigned int* myT = ldsT + wave*1024;
  float be2_r[8], bc1_r[8], wc2_r[8];
  #pragma unroll
  for (int ob = 0; ob < 8; ++ob) {
    be2_r[ob] = be2_l[ob*16 + c16];
    bc1_r[ob] = bc1_l[ob*16 + c16];
    wc2_r[ob] = Wc2_l[ob*16 + c16];
  }
  const int swz = (c16 & 7) << 2;
  const int gw = blockIdx.x*8 + wave;
  const int nw = gridDim.x*8;
  const int ntiles = E >> 5;
  for (int tt = gw; tt < ntiles; tt += nw) {
    int ib = tt << 5;
    int r_[2], c_[2]; float d2_[2], rlx[2], rly[2], rlz[2];
    #pragma unroll
    for (int s = 0; s < 2; ++s) {
      int i = ib + s*16 + c16;
      r_[s] = srow[i]; c_[s] = scol[i];
      float4 xr = x4[r_[s]], xc = x4[c_[s]];
      rlx[s] = xr.x-xc.x; rly[s] = xr.y-xc.y; rlz[s] = xr.z-xc.z;
      d2_[s] = rlx[s]*rlx[s] + rly[s]*rly[s] + rlz[s]*rlz[s];
    }
    // ---- GEMM1: u @ We2 (hi/lo) ----
    f32x4 zero4 = {0.f, 0.f, 0.f, 0.f};
    f32x4 acc[2][8];
    #pragma unroll
    for (int s = 0; s < 2; ++s)
      #pragma unroll
      for (int ob = 0; ob < 8; ++ob) acc[s][ob] = zero4;
    #pragma unroll
    for (int kb = 0; kb < 4; ++kb) {
      int ch0 = kb*32 + g*8;
      float4 w0 = *(const float4*)(wd2_l + ch0);
      float4 w1 = *(const float4*)(wd2_l + ch0 + 4);
      FragU Ah[2], Al[2];
      #pragma unroll
      for (int s = 0; s < 2; ++s) {
        const float4* pr1 = (const float4*)(p1 + (size_t)r_[s]*HID + ch0);
        const float4* pr2 = (const float4*)(p2 + (size_t)c_[s]*HID + ch0);
        float4 a0 = pr1[0], a1 = pr1[1];
        float4 b0 = pr2[0], b1 = pr2[1];
        float d2 = d2_[s];
        float uu[8];
        uu[0] = silu_f(a0.x + b0.x + d2*w0.x);
        uu[1] = silu_f(a0.y + b0.y + d2*w0.y);
        uu[2] = silu_f(a0.z + b0.z + d2*w0.z);
        uu[3] = silu_f(a0.w + b0.w + d2*w0.w);
        uu[4] = silu_f(a1.x + b1.x + d2*w1.x);
        uu[5] = silu_f(a1.y + b1.y + d2*w1.y);
        uu[6] = silu_f(a1.z + b1.z + d2*w1.z);
        uu[7] = silu_f(a1.w + b1.w + d2*w1.w);
        pack8(uu, Ah[s], Al[s]);
      }
      #pragma unroll
      for (int ob = 0; ob < 8; ++ob) {
        FragU Bh, Bl;
        Bh.u = ldsB[(kb*8 + ob)*64 + lane];
        Bl.u = ldsB[2048 + (kb*8 + ob)*64 + lane];
        #pragma unroll
        for (int s = 0; s < 2; ++s) {
          acc[s][ob] = __builtin_amdgcn_mfma_f32_16x16x32_bf16(Al[s].v, Bh.v, acc[s][ob], 0, 0, 0);
          acc[s][ob] = __builtin_amdgcn_mfma_f32_16x16x32_bf16(Ah[s].v, Bl.v, acc[s][ob], 0, 0, 0);
          acc[s][ob] = __builtin_amdgcn_mfma_f32_16x16x32_bf16(Ah[s].v, Bh.v, acc[s][ob], 0, 0, 0);
        }
      }
    }
    // ---- per half: two 64-channel phases through the 4KB tile ----
    #pragma unroll
    for (int s = 0; s < 2; ++s) {
      f32x4 acc2[8];
      #pragma unroll
      for (int ob = 0; ob < 8; ++ob) acc2[ob] = zero4;
      #pragma unroll
      for (int p = 0; p < 2; ++p) {
        // epilogue -> tile (channels p*64 .. p*64+63)
        #pragma unroll
        for (int ob4 = 0; ob4 < 4; ++ob4) {
          int ob = p*4 + ob4;
          #pragma unroll
          for (int r = 0; r < 4; ++r) {
            int row = 4*g + r;
            float mval = silu_f(acc[s][ob][r] + be2_r[ob]);
            myT[(row << 6) + ((ob4*16 + c16) ^ ((row & 7) << 2))] = pack_pair(mval);
          }
        }
        // coalesced m store: 16 rows x 64 ch (4 insts of 4 x 256B segments)
        unsigned int* gout = m_pairs + (size_t)(ib + s*16)*HID + p*64;
        #pragma unroll
        for (int inst = 0; inst < 4; ++inst) {
          int flat = inst*256 + lane*4;
          int row = flat >> 6, col = flat & 63;
          uint4 vv = *(const uint4*)&myT[(row << 6) + (col ^ ((row & 7) << 2))];
          *(uint4*)(gout + (size_t)row*HID + col) = vv;
        }
        // GEMM2 partial: kb = p*2, p*2+1 (Wc1 hi/lo)
        #pragma unroll
        for (int kbl = 0; kbl < 2; ++kbl) {
          int kb = p*2 + kbl;
          int col0 = kbl*32 + g*8;
          uint4 a = *(const uint4*)&myT[(c16 << 6) + (col0 ^ swz)];
          uint4 b = *(const uint4*)&myT[(c16 << 6) + ((col0 + 4) ^ swz)];
          FragU Ah, Al;
          unpack_frags(a, b, Ah, Al);
          #pragma unroll
          for (int ob = 0; ob < 8; ++ob) {
            FragU Bh, Bl;
            Bh.u = ldsB[4096 + (kb*8 + ob)*64 + lane];
            Bl.u = ldsB[6144 + (kb*8 + ob)*64 + lane];
            acc2[ob] = __builtin_amdgcn_mfma_f32_16x16x32_bf16(Al.v, Bh.v, acc2[ob], 0, 0, 0);
            acc2[ob] = __builtin_amdgcn_mfma_f32_16x16x32_bf16(Ah.v, Bl.v, acc2[ob], 0, 0, 0);
            acc2[ob] = __builtin_amdgcn_mfma_f32_16x16x32_bf16(Ah.v, Bh.v, acc2[ob], 0, 0, 0);
          }
        }
      }
      // coef reduce + rc_ws
      float part[4] = {0.f, 0.f, 0.f, 0.f};
      #pragma unroll
      for (int ob = 0; ob < 8; ++ob)
        #pragma unroll
        for (int r = 0; r < 4; ++r) {
          float tv = silu_f(acc2[ob][r] + bc1_r[ob]);
          part[r] += tv * wc2_r[ob];
        }
      #pragma unroll
      for (int r = 0; r < 4; ++r) {
        #pragma unroll
        for (int m = 1; m < 16; m <<= 1) part[r] += __shfl_xor(part[r], m);
      }
      #pragma unroll
      for (int r = 0; r < 4; ++r) {
        float sx = __shfl(rlx[s], 4*g + r);
        float sy = __shfl(rly[s], 4*g + r);
        float sz = __shfl(rlz[s], 4*g + r);
        if (c16 == 0) {
          float cf = part[r];
          rc_ws[ib + s*16 + 4*g + r] = make_float4(sx*cf, sy*cf, sz*cf, 0.f);
        }
      }
    }
  }
}

// ---------------- aggregation (streaming, CSR slot order, 2-edge unrolled) --------
__global__ void agg_kernel(const int* __restrict__ offp,
                           const unsigned int* __restrict__ m_pairs,
                           const float4* __restrict__ rc_ws,
                           float* __restrict__ agg, float4* __restrict__ x4, int V)
{
  int wave = threadIdx.x >> 6, lane = threadIdx.x & 63;
  int v = blockIdx.x*4 + wave;
  if (v >= V) return;
  int s = offp[v], e = offp[v+1];
  float acc0 = 0.f, acc1 = 0.f;
  float rx = 0.f, ry = 0.f, rz = 0.f;
  int i = s;
  for (; i + 2 <= e; i += 2) {
    uint2 mv0 = ((const uint2*)m_pairs)[(size_t)i*64 + lane];
    uint2 mv1 = ((const uint2*)m_pairs)[(size_t)(i+1)*64 + lane];
    float4 rc0 = rc_ws[i];
    float4 rc1 = rc_ws[i+1];
    acc0 += unpack_sum(mv0.x) + unpack_sum(mv1.x);
    acc1 += unpack_sum(mv0.y) + unpack_sum(mv1.y);
    rx += rc0.x + rc1.x; ry += rc0.y + rc1.y; rz += rc0.z + rc1.z;
  }
  if (i < e) {
    uint2 mv = ((const uint2*)m_pairs)[(size_t)i*64 + lane];
    float4 rc = rc_ws[i];
    acc0 += unpack_sum(mv.x);
    acc1 += unpack_sum(mv.y);
    rx += rc.x; ry += rc.y; rz += rc.z;
  }
  ((float2*)agg)[(size_t)v*64 + lane] = make_float2(acc0, acc1);
  if (lane == 0) {
    float4 xv = x4[v];
    xv.x += rx; xv.y += ry; xv.z += rz;
    x4[v] = xv;
  }
}

__global__ void vel_kernel(const float4* __restrict__ x4, const float* __restrict__ pos,
                           float* __restrict__ out, int V) {
  int v = blockIdx.x * blockDim.x + threadIdx.x;
  if (v < V) {
    float4 xv = x4[v];
    out[3*v]   = xv.x - pos[3*v];
    out[3*v+1] = xv.y - pos[3*v+1];
    out[3*v+2] = xv.z - pos[3*v+2];
  }
}

extern "C" void kernel_launch(void* const* d_in, const int* in_sizes, int n_in,
                              void* d_out, int out_size, void* d_ws, size_t ws_size,
                              hipStream_t stream) {
  const float* pos   = (const float*)d_in[0];
  const float* t     = (const float*)d_in[1];
  const float* z     = (const float*)d_in[2];
  const int*   ei    = (const int*)d_in[3];
  const int*   batch = (const int*)d_in[4];
  const float* te_w1 = (const float*)d_in[5];
  const float* te_b1 = (const float*)d_in[6];
  const float* te_w2 = (const float*)d_in[7];
  const float* te_b2 = (const float*)d_in[8];
  const float* cp_w  = (const float*)d_in[9];
  const float* cp_b  = (const float*)d_in[10];
  const float* We1   = (const float*)d_in[11];
  const float* be1   = (const float*)d_in[12];
  const float* We2   = (const float*)d_in[13];
  const float* be2   = (const float*)d_in[14];
  const float* Wc1   = (const float*)d_in[15];
  const float* bc1   = (const float*)d_in[16];
  const float* Wc2   = (const float*)d_in[17];
  const float* Wn1   = (const float*)d_in[18];
  const float* bn1   = (const float*)d_in[19];
  const float* Wn2   = (const float*)d_in[20];
  const float* bn2   = (const float*)d_in[21];

  const int V = in_sizes[4];
  const int E = in_sizes[3] / 2;
  const int* rowp = ei;
  const int* colp = ei + E;

  char* base = (char*)d_ws;
  size_t off_b = 0;
  auto alloc = [&](size_t bytes) -> char* {
    char* p = base + off_b;
    off_b += (bytes + 255) & ~(size_t)255;
    return p;
  };
  float*  h     = (float*) alloc((size_t)V*HID*4);
  float*  pA    = (float*) alloc((size_t)V*HID*4);   // p1, later nu1a tmp
  float*  pB    = (float*) alloc((size_t)V*HID*4);   // p2, later agg
  float4* x4    = (float4*)alloc((size_t)V*16);
  char*   m_buf = alloc((size_t)E*HID*4);            // m pairs (uint), later q (float)
  float4* rc_ws = (float4*)alloc((size_t)E*16);
  float*  hb    = (float*) alloc(8*HID*4);
  int*    cnt   = (int*)   alloc((size_t)V*4);
  int*    offp  = (int*)   alloc((size_t)(V+1)*4);
  int*    fill  = (int*)   alloc((size_t)V*4);
  int*    srow  = (int*)   alloc((size_t)E*4);
  int*    scol  = (int*)   alloc((size_t)E*4);
  unsigned short* wfrag = (unsigned short*)alloc((size_t)NLAY*7*32768*sizeof(unsigned short));
  (void)ws_size; (void)n_in; (void)out_size;

  unsigned int* m_pairs = (unsigned int*)m_buf;
  float* q_buf = (float*)m_buf;

  auto wf = [&](int l, int j) -> unsigned short* {
    return wfrag + ((size_t)(l*7 + j))*32768;
  };

  const int NLDS = 65536;
  const int FLDS = 163840;   // full 160 KiB workgroup LDS
  hipFuncSetAttribute((const void*)ngemm_kernel<0>, hipFuncAttributeMaxDynamicSharedMemorySize, NLDS);
  hipFuncSetAttribute((const void*)ngemm_kernel<1>, hipFuncAttributeMaxDynamicSharedMemorySize, NLDS);
  hipFuncSetAttribute((const void*)ngemm_kernel<2>, hipFuncAttributeMaxDynamicSharedMemorySize, NLDS);
  hipFuncSetAttribute((const void*)ngemm_kernel<3>, hipFuncAttributeMaxDynamicSharedMemorySize, NLDS);
  hipFuncSetAttribute((const void*)edge_fused_kernel, hipFuncAttributeMaxDynamicSharedMemorySize, FLDS);

  hb_kernel<<<8, 128, 0, stream>>>(t, z, te_w1, te_b1, te_w2, te_b2, cp_w, cp_b, hb);
  scatter_h_kernel<<<(V*32 + 255)/256, 256, 0, stream>>>(batch, hb, h, V);
  packx_kernel<<<(V + 255)/256, 256, 0, stream>>>(pos, x4, V);
  hipMemsetAsync(cnt, 0, (size_t)V*4, stream);
  hipMemsetAsync(fill, 0, (size_t)V*4, stream);
  hist_kernel<<<(E + 255)/256, 256, 0, stream>>>(rowp, cnt, E);
  scan_kernel<<<1, 1024, 0, stream>>>(cnt, offp, V);
  scatter_perm_kernel<<<(E + 255)/256, 256, 0, stream>>>(rowp, colp, offp, fill, srow, scol, E);

  // prep all 28 MFMA B-frag streams in one launch
  wprep_all_kernel<<<28*64, 256, 0, stream>>>(We1, We2, Wc1, Wn1, Wn2, wfrag);

  const int ngrid = ((V >> 5) + 7) / 8;    // 32-row tiles, 8 waves/block
  const int egrid = 256;                   // 1 block/CU (full-LDS), grid-stride

  for (int l = 0; l < NLAY; ++l) {
    const float* wd2_l = We1 + (size_t)l*257*HID + 256*HID;
    const float* Wc2_l = Wc2 + (size_t)l*HID;
    const float* be1_l = be1 + l*HID;
    const float* be2_l = be2 + l*HID;
    const float* bc1_l = bc1 + l*HID;
    const float* bn1_l = bn1 + l*HID;
    const float* bn2_l = bn2 + l*HID;

    ngemm_kernel<1><<<ngrid, 512, NLDS, stream>>>(h, wf(l,0), be1_l, nullptr, pA, V);   // p1+be1
    ngemm_kernel<0><<<ngrid, 512, NLDS, stream>>>(h, wf(l,1), nullptr, nullptr, pB, V); // p2
    edge_fused_kernel<<<egrid, 512, FLDS, stream>>>(srow, scol, x4, pA, pB,
                                                    wf(l,2), wf(l,3), wd2_l, be2_l,
                                                    bc1_l, Wc2_l, m_pairs, rc_ws, E);
    agg_kernel<<<(V + 3)/4, 256, 0, stream>>>(offp, m_pairs, rc_ws, pB, x4, V);
    ngemm_kernel<1><<<ngrid, 512, NLDS, stream>>>(h, wf(l,4), bn1_l, nullptr, pA, V);   // tmp
    ngemm_kernel<2><<<ngrid, 512, NLDS, stream>>>(pB, wf(l,5), nullptr, pA, q_buf, V);  // q
    ngemm_kernel<3><<<ngrid, 512, NLDS, stream>>>(q_buf, wf(l,6), bn2_l, nullptr, h, V); // h+=
  }
  vel_kernel<<<(V + 255)/256, 256, 0, stream>>>(x4, pos, (float*)d_out, V);
}